// Round 1
// baseline (467.062 us; speedup 1.0000x reference)
//
#include <hip/hip_runtime.h>

// HyperConnections fused kernel.
// out[(b*S+s)*T+t, d] = res[...] + c[s] * rmsnorm(sum_s h_pre[s]*res[...])[d]
// where c[s] = sum_r Sinkhorn(exp(H_res))[s][r] * 2*sigmoid(H_post[r]).
// Memory-bound: 256 MiB in + 256 MiB out; each input element read once.

#define S_ 4
#define T_ 4096
#define D_ 1024
#define NITER_ 20
#define EPSF_ 1e-5f

__global__ __launch_bounds__(256) void hyperconn_kernel(
    const float* __restrict__ res,
    const float* __restrict__ w,
    const float* __restrict__ hpre_l,
    const float* __restrict__ hpost_l,
    const float* __restrict__ hres,
    float* __restrict__ out)
{
    const int n   = blockIdx.x;          // n = b*T + t
    const int b   = n >> 12;             // T = 4096
    const int t   = n & (T_ - 1);
    const int tid = threadIdx.x;         // 256 threads, one float4 each

    __shared__ float s_c[S_];
    __shared__ float s_part[4];          // one partial per wave (4 waves)

    // ---- thread 0: Sinkhorn on the 4x4 (serial, ~1.6k flops, hidden
    //      under the HBM load latency of the other lanes) ----
    if (tid == 0) {
        float M[S_][S_];
        #pragma unroll
        for (int i = 0; i < S_; ++i)
            #pragma unroll
            for (int j = 0; j < S_; ++j)
                M[i][j] = __expf(hres[i * S_ + j]);
        for (int it = 0; it < NITER_; ++it) {
            #pragma unroll
            for (int i = 0; i < S_; ++i) {
                float srow = M[i][0] + M[i][1] + M[i][2] + M[i][3];
                float inv  = 1.0f / (srow + EPSF_);
                M[i][0] *= inv; M[i][1] *= inv; M[i][2] *= inv; M[i][3] *= inv;
            }
            #pragma unroll
            for (int j = 0; j < S_; ++j) {
                float scol = M[0][j] + M[1][j] + M[2][j] + M[3][j];
                float inv  = 1.0f / (scol + EPSF_);
                M[0][j] *= inv; M[1][j] *= inv; M[2][j] *= inv; M[3][j] *= inv;
            }
        }
        #pragma unroll
        for (int s = 0; s < S_; ++s) {
            float c = 0.0f;
            #pragma unroll
            for (int r = 0; r < S_; ++r) {
                float hp = 2.0f / (1.0f + __expf(-hpost_l[r]));
                c += M[s][r] * hp;
            }
            s_c[s] = c;
        }
    }

    // ---- every thread: h_pre (4 sigmoids, cheap & uniform) ----
    float hpre[S_];
    #pragma unroll
    for (int s = 0; s < S_; ++s)
        hpre[s] = 1.0f / (1.0f + __expf(-hpre_l[s]));

    const float4* res4 = reinterpret_cast<const float4*>(res);
    const float4* w4   = reinterpret_cast<const float4*>(w);
    float4*       out4 = reinterpret_cast<float4*>(out);

    const int    D4      = D_ / 4;                      // 256 float4 per row
    const size_t rowbase = (size_t)(b * S_) * T_ + t;   // row of stream 0

    // ---- load all 4 stream rows into registers (read each element once) ----
    float4 r[S_];
    #pragma unroll
    for (int s = 0; s < S_; ++s)
        r[s] = res4[(rowbase + (size_t)s * T_) * D4 + tid];

    // ---- aggregate ----
    float4 agg;
    agg.x = hpre[0]*r[0].x + hpre[1]*r[1].x + hpre[2]*r[2].x + hpre[3]*r[3].x;
    agg.y = hpre[0]*r[0].y + hpre[1]*r[1].y + hpre[2]*r[2].y + hpre[3]*r[3].y;
    agg.z = hpre[0]*r[0].z + hpre[1]*r[1].z + hpre[2]*r[2].z + hpre[3]*r[3].z;
    agg.w = hpre[0]*r[0].w + hpre[1]*r[1].w + hpre[2]*r[2].w + hpre[3]*r[3].w;

    // ---- sum of squares over D=1024: wave shuffle + LDS across 4 waves ----
    float ssq = agg.x*agg.x + agg.y*agg.y + agg.z*agg.z + agg.w*agg.w;
    #pragma unroll
    for (int off = 32; off >= 1; off >>= 1)
        ssq += __shfl_down(ssq, off, 64);
    const int lane = tid & 63;
    const int wv   = tid >> 6;
    if (lane == 0) s_part[wv] = ssq;
    __syncthreads();                     // also publishes s_c[] from thread 0
    const float tot     = s_part[0] + s_part[1] + s_part[2] + s_part[3];
    const float inv_rms = rsqrtf(tot * (1.0f / (float)D_) + EPSF_);

    // ---- normalize, scale by weight, distribute with c[s], add residual ----
    const float4 wt = w4[tid];
    float4 nrm;
    nrm.x = agg.x * inv_rms * wt.x;
    nrm.y = agg.y * inv_rms * wt.y;
    nrm.z = agg.z * inv_rms * wt.z;
    nrm.w = agg.w * inv_rms * wt.w;

    #pragma unroll
    for (int s = 0; s < S_; ++s) {
        const float c = s_c[s];
        float4 o;
        o.x = r[s].x + nrm.x * c;
        o.y = r[s].y + nrm.y * c;
        o.z = r[s].z + nrm.z * c;
        o.w = r[s].w + nrm.w * c;
        out4[(rowbase + (size_t)s * T_) * D4 + tid] = o;
    }
}

extern "C" void kernel_launch(void* const* d_in, const int* in_sizes, int n_in,
                              void* d_out, int out_size, void* d_ws, size_t ws_size,
                              hipStream_t stream) {
    const float* res     = (const float*)d_in[0];   // (B*S, T, D) f32
    const float* weight  = (const float*)d_in[1];   // (D,) f32
    const float* hpre_l  = (const float*)d_in[2];   // (S,) f32
    const float* hpost_l = (const float*)d_in[3];   // (S,) f32
    const float* hres    = (const float*)d_in[4];   // (S,S) f32
    float*       out     = (float*)d_out;

    // grid = B*T rows; B*T = total_elems / (S*D)
    const int n_rows = in_sizes[0] / (S_ * D_);     // 16384 for B=4,T=4096
    hyperconn_kernel<<<n_rows, 256, 0, stream>>>(res, weight, hpre_l, hpost_l, hres, out);
}